// Round 1
// baseline (404.128 us; speedup 1.0000x reference)
//
#include <hip/hip_runtime.h>
#include <math.h>

#define NN 20000
#define EE 320000
#define ETOT 340000
#define GG 64
#define INCH 128
#define HIDC 64
#define NH 8
#define HC 512            // NH*HIDC
#define SLOPE 0.2f
#define SMEPS 1e-16f
#define NEG_INF (-3.402823466e38f)

// ---------------- CSR build ----------------
__global__ void k_hist(const int* __restrict__ ei, int* __restrict__ deg) {
  int i = blockIdx.x * 256 + threadIdx.x;
  if (i >= ETOT) return;
  int d = (i < EE) ? ei[EE + i] : (i - EE);
  atomicAdd(&deg[d], 1);
}

__global__ void k_scan(const int* __restrict__ deg, int* __restrict__ rowstart) {
  __shared__ int wsum[16];
  __shared__ int carry_sh;
  int tid = threadIdx.x;
  int lane = tid & 63, w = tid >> 6;
  if (tid == 0) { carry_sh = 0; rowstart[0] = 0; }
  __syncthreads();
  for (int base = 0; base < NN; base += 1024) {
    int v = (base + tid < NN) ? deg[base + tid] : 0;
    int s = v;
#pragma unroll
    for (int off = 1; off < 64; off <<= 1) {
      int t = __shfl_up(s, off);
      if (lane >= off) s += t;
    }
    if (lane == 63) wsum[w] = s;
    __syncthreads();
    if (w == 0 && lane < 16) {
      int t = wsum[lane];
#pragma unroll
      for (int off = 1; off < 16; off <<= 1) {
        int u = __shfl_up(t, off);
        if (lane >= off) t += u;
      }
      wsum[lane] = t;
    }
    __syncthreads();
    int waveoff = (w == 0) ? 0 : wsum[w - 1];
    int incl = s + waveoff + carry_sh;
    if (base + tid < NN) rowstart[base + tid + 1] = incl;
    __syncthreads();
    if (tid == 1023) carry_sh = incl;
    __syncthreads();
  }
}

__global__ void k_fill(const int* __restrict__ ei, const int* __restrict__ rowstart,
                       int* __restrict__ wcur, int* __restrict__ csr) {
  int i = blockIdx.x * 256 + threadIdx.x;
  if (i >= ETOT) return;
  int s, d;
  if (i < EE) { s = ei[i]; d = ei[EE + i]; } else { s = i - EE; d = s; }
  int pos = rowstart[d] + atomicAdd(&wcur[d], 1);
  csr[pos] = s;
}

// ---------------- GEMM1: h1 = x @ W1^T, fused att logits ----------------
__global__ __launch_bounds__(256) void k_gemm1(
    const float* __restrict__ x, const float* __restrict__ W1,
    const float* __restrict__ att_s, const float* __restrict__ att_d,
    float* __restrict__ h1, float* __restrict__ as1, float* __restrict__ ad1) {
  __shared__ float xs[32][128];   // 16 KB
  __shared__ float ws[16][513];   // 32.8 KB, +1 pad breaks bank collisions on transpose-write
  int tid = threadIdx.x;
  int tx = tid & 63, ty = tid >> 6;
  int m0 = blockIdx.x * 32;

  for (int p = 0; p < 4; ++p) {
    int idx4 = tid + p * 256;
    int nl = idx4 >> 5, kq = idx4 & 31;
    *(float4*)&xs[nl][kq * 4] = *(const float4*)(x + (size_t)(m0 + nl) * INCH + kq * 4);
  }

  float acc[8][8];
  for (int i = 0; i < 8; ++i)
    for (int j = 0; j < 8; ++j) acc[i][j] = 0.f;

  for (int kt = 0; kt < 8; ++kt) {
    __syncthreads();
    for (int p = 0; p < 8; ++p) {
      int idx4 = tid + p * 256;
      int o = idx4 >> 2, kq = idx4 & 3;
      const float4 wv4 = *(const float4*)(W1 + (size_t)o * INCH + kt * 16 + kq * 4);
      ws[kq * 4 + 0][o] = wv4.x; ws[kq * 4 + 1][o] = wv4.y;
      ws[kq * 4 + 2][o] = wv4.z; ws[kq * 4 + 3][o] = wv4.w;
    }
    __syncthreads();
#pragma unroll
    for (int kk = 0; kk < 16; ++kk) {
      float wv[8], xv[8];
#pragma unroll
      for (int j = 0; j < 8; ++j) wv[j] = ws[kk][tx + 64 * j];
#pragma unroll
      for (int i = 0; i < 8; ++i) xv[i] = xs[ty * 8 + i][kt * 16 + kk];
#pragma unroll
      for (int i = 0; i < 8; ++i)
#pragma unroll
        for (int j = 0; j < 8; ++j) acc[i][j] = fmaf(xv[i], wv[j], acc[i][j]);
    }
  }

  for (int i = 0; i < 8; ++i) {
    int n = m0 + ty * 8 + i;
#pragma unroll
    for (int j = 0; j < 8; ++j) {
      float v = acc[i][j];
      h1[(size_t)n * HC + tx + 64 * j] = v;
      float ps = v * att_s[j * 64 + tx];
      float pd = v * att_d[j * 64 + tx];
#pragma unroll
      for (int off = 32; off; off >>= 1) {
        ps += __shfl_xor(ps, off);
        pd += __shfl_xor(pd, off);
      }
      if (tx == 0) { as1[(size_t)n * NH + j] = ps; ad1[(size_t)n * NH + j] = pd; }
    }
  }
}

// ---------------- GEMM2: h2 = xmid @ W2^T, fused att logits ----------------
__global__ __launch_bounds__(256) void k_gemm2(
    const float* __restrict__ xm, const float* __restrict__ W2,
    const float* __restrict__ att_s, const float* __restrict__ att_d,
    float* __restrict__ h2, float* __restrict__ as2, float* __restrict__ ad2) {
  __shared__ float xs[32][128];
  __shared__ float ws[128][65];
  int tid = threadIdx.x;
  int tx = tid & 63, ty = tid >> 6;
  int m0 = blockIdx.x * 32;

  float acc[8];
  for (int i = 0; i < 8; ++i) acc[i] = 0.f;

  for (int kt = 0; kt < 4; ++kt) {
    __syncthreads();
    for (int p = 0; p < 4; ++p) {
      int idx4 = tid + p * 256;
      int nl = idx4 >> 5, kq = idx4 & 31;
      *(float4*)&xs[nl][kq * 4] = *(const float4*)(xm + (size_t)(m0 + nl) * HC + kt * 128 + kq * 4);
    }
    for (int p = 0; p < 8; ++p) {
      int idx4 = tid + p * 256;
      int o = idx4 >> 5, kq = idx4 & 31;
      const float4 wv4 = *(const float4*)(W2 + (size_t)o * HC + kt * 128 + kq * 4);
      ws[kq * 4 + 0][o] = wv4.x; ws[kq * 4 + 1][o] = wv4.y;
      ws[kq * 4 + 2][o] = wv4.z; ws[kq * 4 + 3][o] = wv4.w;
    }
    __syncthreads();
#pragma unroll 8
    for (int k4 = 0; k4 < 128; k4 += 4) {
      float wq[4];
#pragma unroll
      for (int q = 0; q < 4; ++q) wq[q] = ws[k4 + q][tx];
#pragma unroll
      for (int i = 0; i < 8; ++i) {
        const float4 xq = *(const float4*)&xs[ty * 8 + i][k4];
        acc[i] = fmaf(xq.x, wq[0], acc[i]);
        acc[i] = fmaf(xq.y, wq[1], acc[i]);
        acc[i] = fmaf(xq.z, wq[2], acc[i]);
        acc[i] = fmaf(xq.w, wq[3], acc[i]);
      }
    }
  }

  float asw = att_s[tx], adw = att_d[tx];
  for (int i = 0; i < 8; ++i) {
    int n = m0 + ty * 8 + i;
    h2[(size_t)n * HIDC + tx] = acc[i];
    float ps = acc[i] * asw, pd = acc[i] * adw;
#pragma unroll
    for (int off = 32; off; off >>= 1) {
      ps += __shfl_xor(ps, off);
      pd += __shfl_xor(pd, off);
    }
    if (tx == 0) { as2[n] = ps; ad2[n] = pd; }
  }
}

// ---------------- Layer-1 fused softmax + aggregate (block per node) ----------------
#define CH1 256
__global__ __launch_bounds__(256) void k_node1(
    const float* __restrict__ h1, const float* __restrict__ as1, const float* __restrict__ ad1,
    const int* __restrict__ rowstart, const int* __restrict__ csr,
    const float* __restrict__ b1, float* __restrict__ xmid) {
  int n = blockIdx.x;
  int tid = threadIdx.x;
  int rs = rowstart[n], re = rowstart[n + 1];
  __shared__ float e_lds[CH1][NH + 1];  // +1 pad: conflict-free strided column access
  __shared__ int s_sh[CH1];
  __shared__ float ad_sh[NH], m_sh[NH], z_sh[NH], f_sh[NH], c_sh[NH];
  if (tid < NH) { ad_sh[tid] = ad1[(size_t)n * NH + tid]; m_sh[tid] = NEG_INF; z_sh[tid] = 0.f; }
  __syncthreads();
  int myh = tid >> 5;          // head owned by this 32-lane group == head of c0
  int lane32 = tid & 31;
  int c0 = tid * 2;
  float accx = 0.f, accy = 0.f;

  for (int base = rs; base < re; base += CH1) {
    int cn = min(CH1, re - base);
    if (tid < cn) {
      int s = csr[base + tid];
      s_sh[tid] = s;
      const float4 a0 = *(const float4*)(as1 + (size_t)s * NH);
      const float4 a1 = *(const float4*)(as1 + (size_t)s * NH + 4);
      float ev[8] = {a0.x + ad_sh[0], a0.y + ad_sh[1], a0.z + ad_sh[2], a0.w + ad_sh[3],
                     a1.x + ad_sh[4], a1.y + ad_sh[5], a1.z + ad_sh[6], a1.w + ad_sh[7]};
#pragma unroll
      for (int h = 0; h < NH; ++h) {
        float e = ev[h];
        e_lds[tid][h] = (e > 0.f) ? e : SLOPE * e;
      }
    }
    __syncthreads();
    // per-head chunk max (group g handles head g)
    float mv = NEG_INF;
    for (int j = lane32; j < cn; j += 32) mv = fmaxf(mv, e_lds[j][myh]);
#pragma unroll
    for (int off = 16; off; off >>= 1) mv = fmaxf(mv, __shfl_xor(mv, off));
    if (lane32 == 0) c_sh[myh] = mv;
    __syncthreads();
    if (tid < NH) {
      float mo = m_sh[tid];
      float mn = fmaxf(mo, c_sh[tid]);
      float f = (mo <= NEG_INF) ? 0.f : __expf(mo - mn);
      f_sh[tid] = f; m_sh[tid] = mn; z_sh[tid] *= f;
    }
    __syncthreads();
    float mn = m_sh[myh];
    float zs = 0.f;
    for (int j = lane32; j < cn; j += 32) {
      float p = __expf(e_lds[j][myh] - mn);
      e_lds[j][myh] = p;
      zs += p;
    }
#pragma unroll
    for (int off = 16; off; off >>= 1) zs += __shfl_xor(zs, off);
    float f = f_sh[myh];
    accx *= f; accy *= f;
    if (lane32 == 0) z_sh[myh] += zs;
    __syncthreads();
    // weighted aggregation: every thread owns 2 channels
    for (int j = 0; j < cn; ++j) {
      float p = e_lds[j][myh];
      const float2 hv = *(const float2*)(h1 + (size_t)s_sh[j] * HC + c0);
      accx = fmaf(p, hv.x, accx);
      accy = fmaf(p, hv.y, accy);
    }
    __syncthreads();
  }
  float inv = 1.f / (z_sh[myh] + SMEPS);
  float vx = fmaxf(accx * inv + b1[c0], 0.f);
  float vy = fmaxf(accy * inv + b1[c0 + 1], 0.f);
  float2 o2; o2.x = vx; o2.y = vy;
  *(float2*)(xmid + (size_t)n * HC + c0) = o2;
}

// ---------------- Layer-2 fused softmax + aggregate (wave per node) ----------------
__global__ __launch_bounds__(64) void k_node2(
    const float* __restrict__ h2, const float* __restrict__ as2, const float* __restrict__ ad2,
    const int* __restrict__ rowstart, const int* __restrict__ csr,
    const float* __restrict__ b2, float* __restrict__ out) {
  int n = blockIdx.x;
  int lane = threadIdx.x;
  int rs = rowstart[n], re = rowstart[n + 1];
  __shared__ float p_sh[64];
  __shared__ int s_sh[64];
  float ad = ad2[n];
  float m = NEG_INF, z = 0.f, acc = 0.f;
  for (int base = rs; base < re; base += 64) {
    int cn = min(64, re - base);
    float e = NEG_INF;
    int s = 0;
    if (lane < cn) {
      s = csr[base + lane];
      float t = as2[s] + ad;
      e = (t > 0.f) ? t : SLOPE * t;
    }
    float cm = e;
#pragma unroll
    for (int off = 32; off; off >>= 1) cm = fmaxf(cm, __shfl_xor(cm, off));
    float mn = fmaxf(m, cm);
    float f = (m <= NEG_INF) ? 0.f : __expf(m - mn);
    float p = (lane < cn) ? __expf(e - mn) : 0.f;
    float zc = p;
#pragma unroll
    for (int off = 32; off; off >>= 1) zc += __shfl_xor(zc, off);
    z = z * f + zc;
    acc *= f;
    m = mn;
    p_sh[lane] = p; s_sh[lane] = s;
    __syncthreads();
    for (int j = 0; j < cn; ++j)
      acc = fmaf(p_sh[j], h2[(size_t)s_sh[j] * HIDC + lane], acc);
    __syncthreads();
  }
  out[(size_t)n * HIDC + lane] = acc / (z + SMEPS) + b2[lane];
}

// ---------------- mean pool (block per graph; batch is sorted) ----------------
__device__ inline int lowerb(const int* a, int n, int v) {
  int lo = 0, hi = n;
  while (lo < hi) { int mid = (lo + hi) >> 1; if (a[mid] < v) lo = mid + 1; else hi = mid; }
  return lo;
}

__global__ __launch_bounds__(256) void k_pool(const float* __restrict__ xm,
                                              const int* __restrict__ batch,
                                              float* __restrict__ out) {
  int g = blockIdx.x;
  int tid = threadIdx.x;
  int lo = lowerb(batch, NN, g);
  int hi = lowerb(batch, NN, g + 1);
  float inv = 1.f / fmaxf((float)(hi - lo), 1.f);
  int c = tid * 2;
  float sx = 0.f, sy = 0.f;
  int n = lo;
  for (; n + 4 <= hi; n += 4) {
    float2 v0 = *(const float2*)(xm + (size_t)(n + 0) * HC + c);
    float2 v1 = *(const float2*)(xm + (size_t)(n + 1) * HC + c);
    float2 v2 = *(const float2*)(xm + (size_t)(n + 2) * HC + c);
    float2 v3 = *(const float2*)(xm + (size_t)(n + 3) * HC + c);
    sx += (v0.x + v1.x) + (v2.x + v3.x);
    sy += (v0.y + v1.y) + (v2.y + v3.y);
  }
  for (; n < hi; ++n) {
    float2 v = *(const float2*)(xm + (size_t)n * HC + c);
    sx += v.x; sy += v.y;
  }
  out[(size_t)g * HC + c] = sx * inv;
  out[(size_t)g * HC + c + 1] = sy * inv;
}

extern "C" void kernel_launch(void* const* d_in, const int* in_sizes, int n_in,
                              void* d_out, int out_size, void* d_ws, size_t ws_size,
                              hipStream_t stream) {
  const float* x     = (const float*)d_in[0];
  const int*   ei    = (const int*)d_in[1];
  const int*   batch = (const int*)d_in[2];
  const float* W1    = (const float*)d_in[3];
  const float* atts1 = (const float*)d_in[4];
  const float* attd1 = (const float*)d_in[5];
  const float* b1    = (const float*)d_in[6];
  const float* W2    = (const float*)d_in[7];
  const float* atts2 = (const float*)d_in[8];
  const float* attd2 = (const float*)d_in[9];
  const float* b2    = (const float*)d_in[10];
  float* out = (float*)d_out;

  float* ws = (float*)d_ws;
  size_t off = 0;
  float* h1   = ws + off; off += (size_t)NN * HC;     // 10.24M
  float* xmid = ws + off; off += (size_t)NN * HC;     // 10.24M
  float* h2   = ws + off; off += (size_t)NN * HIDC;   // 1.28M
  float* as1  = ws + off; off += (size_t)NN * NH;
  float* ad1  = ws + off; off += (size_t)NN * NH;
  float* as2  = ws + off; off += NN;
  float* ad2  = ws + off; off += NN;
  int* deg      = (int*)(ws + off); off += NN;
  int* wcur     = (int*)(ws + off); off += NN;        // adjacent to deg: one memset
  int* rowstart = (int*)(ws + off); off += NN + 4;
  int* csr      = (int*)(ws + off); off += ETOT;

  hipMemsetAsync(deg, 0, sizeof(int) * 2 * NN, stream);
  k_hist<<<(ETOT + 255) / 256, 256, 0, stream>>>(ei, deg);
  k_scan<<<1, 1024, 0, stream>>>(deg, rowstart);
  k_fill<<<(ETOT + 255) / 256, 256, 0, stream>>>(ei, rowstart, wcur, csr);

  k_gemm1<<<NN / 32, 256, 0, stream>>>(x, W1, atts1, attd1, h1, as1, ad1);
  k_node1<<<NN, 256, 0, stream>>>(h1, as1, ad1, rowstart, csr, b1, xmid);
  k_pool<<<GG, 256, 0, stream>>>(xmid, batch, out);
  k_gemm2<<<NN / 32, 256, 0, stream>>>(xmid, W2, atts2, attd2, h2, as2, ad2);
  k_node2<<<NN, 64, 0, stream>>>(h2, as2, ad2, rowstart, csr, b2, out + (size_t)GG * HC);
}